// Round 8
// baseline (216.386 us; speedup 1.0000x reference)
//
#include <hip/hip_runtime.h>
#include <hip/hip_bf16.h>

#define B_SZ   2
#define SEQ    1024
#define DMODEL 1024
#define DINNER 2048
#define DSTATE 16
#define DCONV  4
#define DTRANK 64
#define BLROWS (B_SZ*SEQ)
#define NCHUNK 32
#define TCHUNK (SEQ/NCHUNK) // 32
#define NSLICE 16           // dbc split-K partials
#define LOG2E 1.44269504088896f

using floatx4 = __attribute__((ext_vector_type(4))) float;
using short8  = __attribute__((ext_vector_type(8))) short;
using us8     = __attribute__((ext_vector_type(8))) unsigned short;
using us4     = __attribute__((ext_vector_type(4))) unsigned short;

__device__ __forceinline__ float softplus_f(float x) {
    return fmaxf(x, 0.f) + log1pf(__expf(-fabsf(x)));
}
__device__ __forceinline__ float silu_f(float x) {
    return x / (1.f + __expf(-x));
}
__device__ __forceinline__ short bfs(float x) {
    union { __hip_bfloat16 h; short s; } u;
    u.h = __float2bfloat16(x);
    return u.s;
}
__device__ __forceinline__ float b2f(unsigned short s) {
    union { float f; unsigned u; } x;
    x.u = ((unsigned)s) << 16;
    return x.f;
}
__device__ __forceinline__ void gld16(const void* g, void* l) {
    __builtin_amdgcn_global_load_lds((const __attribute__((address_space(1))) void*)g,
                                     (__attribute__((address_space(3))) void*)l,
                                     16, 0, 0);
}
// e[n] = r^(n+1), log-depth (max 4 dependent muls)
__device__ __forceinline__ void pow_chain(float r, float* e) {
    float r2 = r*r, r4 = r2*r2, r8 = r4*r4;
    e[0] = r;      e[1] = r2;     e[2] = r*r2;   e[3] = r4;
    e[4] = r*r4;   e[5] = r2*r4;  e[6] = e[2]*r4; e[7] = r8;
    e[8] = r*r8;   e[9] = r2*r8;  e[10] = e[2]*r8; e[11] = r4*r8;
    e[12] = e[4]*r8; e[13] = e[5]*r8; e[14] = e[6]*r8; e[15] = r8*r8;
}
__device__ __forceinline__ void cast8(const float* src, unsigned short* dst, int i) {
    const float* p = src + (size_t)i*8;
    float4 a = *(const float4*)p, b = *(const float4*)(p+4);
    us8 o;
    o[0]=(unsigned short)bfs(a.x); o[1]=(unsigned short)bfs(a.y);
    o[2]=(unsigned short)bfs(a.z); o[3]=(unsigned short)bfs(a.w);
    o[4]=(unsigned short)bfs(b.x); o[5]=(unsigned short)bfs(b.y);
    o[6]=(unsigned short)bfs(b.z); o[7]=(unsigned short)bfs(b.w);
    *(us8*)(dst + (size_t)i*8) = o;
}

// ---------- fused init: 5 casts, range-partitioned ----------
#define G0 (BLROWS*DMODEL/8)       // x cast
#define G1 (2*DINNER*DMODEL/8)     // W_in cast
#define G2 (96*DINNER/8)           // W_x cast
#define G3 (DINNER*DTRANK/8)       // W_dt cast
#define G4 (DMODEL*DINNER/8)       // W_out cast
#define GTOT (G0+G1+G2+G3+G4)
__global__ __launch_bounds__(256)
void init_kernel(const float* __restrict__ x, const float* __restrict__ W_in,
                 const float* __restrict__ W_x, const float* __restrict__ W_dt,
                 const float* __restrict__ W_out,
                 unsigned short* xH, unsigned short* WinH, unsigned short* WxH,
                 unsigned short* WdtH, unsigned short* WoutH)
{
    int i = blockIdx.x*256 + threadIdx.x;
    if (i < G0) { cast8(x, xH, i); return; }            i -= G0;
    if (i < G1) { cast8(W_in, WinH, i); return; }       i -= G1;
    if (i < G2) { cast8(W_x, WxH, i); return; }         i -= G2;
    if (i < G3) { cast8(W_dt, WdtH, i); return; }       i -= G3;
    if (i < G4) { cast8(W_out, WoutH, i); }
}

// ---------- TN MFMA GEMM, double-buffered 2-phase K-loop, tile TM x TN, BK=32 ----------
// EPI: 5 = split col<DINNER -> outH else outH2 (ld DINNER), bf16
//      8 = softplus(v + bias[col]) -> bf16 packed layout [b][l/8][DINNER][8] (coalesced)
//      9 = plain f32 store to outF + blockIdx.z*M*N (partials / direct out)
template<int TM, int TN, int EPI, bool NGUARD>
__global__ __launch_bounds__(256)
void gemm_tn(const __hip_bfloat16* __restrict__ Ag, const __hip_bfloat16* __restrict__ Bg,
             int M, int N, int K, int kslice,
             float* __restrict__ outF,
             __hip_bfloat16* __restrict__ outH,
             __hip_bfloat16* __restrict__ outH2,
             const float* __restrict__ bias)
{
    constexpr int AG  = TM/64;        // A-tile 64-row stage groups
    constexpr int EB  = TN/64;        // B-tile 64-row stage groups
    constexpr int MF  = TM/32;        // frag-rows per wave
    constexpr int NF  = TN/32;        // frag-cols per wave
    constexpr int SM_SZ = 2*TM*32 + 2*TN*32;
    __shared__ short smem[SM_SZ];
    auto As = (short(*)[TM*32])smem;
    auto Bs = (short(*)[TN*32])(smem + 2*TM*32);

    const int tid  = threadIdx.x;
    const int lane = tid & 63, wave = tid >> 6;
    const int bm0  = blockIdx.x * TM;
    const int bn0  = blockIdx.y * TN;
    const int kbeg = blockIdx.z * kslice;
    const int kend = kbeg + kslice;
    const int wrow = (wave >> 1) * (TM/2), wcol = (wave & 1) * (TN/2);
    const int lrow = lane & 15, quad = lane >> 4;

    const int srow = wave*16 + (lane >> 2);
    const int scol = (lane & 3) * 8;

    const __hip_bfloat16* ga0 = Ag + (size_t)(bm0 + srow)*K      + scol;
    const __hip_bfloat16* ga1 = (AG > 1) ? Ag + (size_t)(bm0 + srow + 64)*K + scol : nullptr;
    const __hip_bfloat16* gb0 = Bg + (size_t)(bn0 + srow)*K      + scol;
    const __hip_bfloat16* gb1 = (EB > 1) ? Bg + (size_t)(bn0 + srow + 64)*K + scol : nullptr;
    const bool b0ok = !NGUARD || (bn0 + wave*16) < N;       // wave-uniform (16-row granules)
    const bool b1ok = (EB > 1) && (!NGUARD || (bn0 + wave*16 + 64) < N);

    auto stage = [&](int c, int k0) {
        gld16(ga0 + k0, &As[c][(wave*16)*32]);
        if (AG > 1) gld16(ga1 + k0, &As[c][(wave*16 + 64)*32]);
        if (b0ok) gld16(gb0 + k0, &Bs[c][(wave*16)*32]);
        if (EB > 1 && b1ok) gld16(gb1 + k0, &Bs[c][(wave*16 + 64)*32]);
    };

    floatx4 acc[MF][NF] = {};

    // prologue: stage first tile, drain, then 2-phase loop (one barrier per K-step)
    stage(0, kbeg);
    __syncthreads();
    int cur = 0;
    for (int k0 = kbeg; k0 < kend; k0 += 32) {
        if (k0 + 32 < kend) stage(cur ^ 1, k0 + 32);   // next-tile loads in flight
        short8 af[MF], bf[NF];
        #pragma unroll
        for (int i = 0; i < MF; i++)
            af[i] = *(const short8*)&As[cur][(wrow + i*16 + lrow)*32 + quad*8];
        #pragma unroll
        for (int j = 0; j < NF; j++)
            bf[j] = *(const short8*)&Bs[cur][(wcol + j*16 + lrow)*32 + quad*8];
        #pragma unroll
        for (int i = 0; i < MF; i++)
            #pragma unroll
            for (int j = 0; j < NF; j++)
                acc[i][j] = __builtin_amdgcn_mfma_f32_16x16x32_bf16(af[i], bf[j], acc[i][j], 0, 0, 0);
        __syncthreads();   // drains next-tile loads (they had MFMA time to land)
        cur ^= 1;
    }

    const int rq = quad * 4;
    if constexpr (EPI == 8) {
        // softplus -> bf16 into LDS transpose buffer t[TN][TM+8], then write
        // packed layout [b][l/8][DINNER][8]: granule (lchunk, d) = 16B, coalesced.
        constexpr int TSTR = TM + 8;               // row stride 144B (16B multiple)
        static_assert(TN*TSTR <= SM_SZ, "transpose buffer fits");
        short* t = smem;
        #pragma unroll
        for (int i = 0; i < MF; i++) {
            #pragma unroll
            for (int j = 0; j < NF; j++) {
                int cl = wcol + j*16 + lrow;       // local d
                int rl = wrow + i*16 + rq;         // local l (us4-aligned)
                us4 pk;
                #pragma unroll
                for (int r = 0; r < 4; r++)
                    pk[r] = (unsigned short)bfs(softplus_f(acc[i][j][r] + bias[bn0 + cl]));
                *(us4*)&t[cl*TSTR + rl] = pk;
            }
        }
        __syncthreads();
        const int bb = bm0 >> 10, lb = bm0 & (SEQ-1);
        constexpr int NGR  = (TM/8)*TN;            // granules in tile
        constexpr int ITER = NGR/256;
        #pragma unroll
        for (int it = 0; it < ITER; ++it) {
            int g   = it*256 + tid;
            int dd  = g % TN;                      // consecutive lanes -> consecutive d
            int lch = g / TN;
            us8 v = *(const us8*)&t[dd*TSTR + lch*8];
            size_t gr = ((size_t)bb*(SEQ>>3) + (lb>>3) + lch)*DINNER + (bn0 + dd);
            *(us8*)((unsigned short*)outH + gr*8) = v;
        }
    } else {
        #pragma unroll
        for (int i = 0; i < MF; i++) {
            #pragma unroll
            for (int j = 0; j < NF; j++) {
                int col = bn0 + wcol + j*16 + lrow;
                if (NGUARD && col >= N) continue;
                #pragma unroll
                for (int r = 0; r < 4; r++) {
                    int row = bm0 + wrow + i*16 + rq + r;
                    float v = acc[i][j][r];
                    if constexpr (EPI == 5) {
                        if (col < DINNER)
                            outH[(size_t)row*DINNER + col] = __float2bfloat16(v);
                        else
                            outH2[(size_t)row*DINNER + (col - DINNER)] = __float2bfloat16(v);
                    } else if constexpr (EPI == 9) {
                        outF[(size_t)blockIdx.z*M*N + (size_t)row*N + col] = v;
                    }
                }
            }
        }
    }
}

// ---------- dbc split-K reduce + dt cvt (fused) ----------
__global__ __launch_bounds__(192)
void dbc_reduce_kernel(const float* __restrict__ part, float* __restrict__ dbc,
                       __hip_bfloat16* __restrict__ dtH)
{
    const int tid = threadIdx.x;
    const int r2  = (tid >= 96) ? 1 : 0;
    const int col = tid - 96*r2;
    const int row = blockIdx.x*2 + r2;
    const size_t idx = (size_t)row*96 + col;
    float s = 0.f;
    #pragma unroll
    for (int z = 0; z < NSLICE; z++)
        s += part[(size_t)z*(BLROWS*96) + idx];
    dbc[idx] = s;
    if (col < DTRANK)
        dtH[(size_t)row*DTRANK + col] = __float2bfloat16(s);
}

// ---------- fused conv+silu+transpose: xbufN -> xsN (normal) + xsT (packed) ----------
__global__ __launch_bounds__(256)
void conv_transpose_kernel(const unsigned short* __restrict__ xbufN,
                           const float* __restrict__ cw,
                           const float* __restrict__ cb,
                           unsigned short* __restrict__ xsN,
                           unsigned short* __restrict__ xsT)
{
    __shared__ unsigned short t[67*68];    // rows l0-3 .. l0+63
    __shared__ unsigned short t2[64*68];
    const int tid = threadIdx.x;
    const int l0 = blockIdx.x * 64, d0 = blockIdx.y * 64, b = blockIdx.z;

    const int lc4 = (tid & 15) * 4;
    for (int r = tid >> 4; r < 67; r += 16) {
        int lg = l0 - 3 + r;
        us4 v = {0,0,0,0};
        if (lg >= 0)
            v = *(const us4*)&xbufN[((size_t)(b*SEQ + lg))*DINNER + d0 + lc4];
        *(us4*)&t[r*68 + lc4] = v;
    }
    __syncthreads();

    const int dd = tid & 63;
    float4 w4 = *(const float4*)&cw[(d0 + dd)*4];
    float  bb = cb[d0 + dd];
    #pragma unroll 4
    for (int rr = tid >> 6; rr < 64; rr += 4) {
        float acc = bb;
        acc += w4.x * b2f(t[(rr+0)*68 + dd]);
        acc += w4.y * b2f(t[(rr+1)*68 + dd]);
        acc += w4.z * b2f(t[(rr+2)*68 + dd]);
        acc += w4.w * b2f(t[(rr+3)*68 + dd]);
        unsigned short h = (unsigned short)bfs(silu_f(acc));
        t2[rr*68 + dd] = h;
        xsN[((size_t)(b*SEQ + l0 + rr))*DINNER + d0 + dd] = h;
    }
    __syncthreads();

    // packed layout [b][l/8][DINNER][8]: granule (lchunk, d), coalesced us8 writes
    #pragma unroll
    for (int it = 0; it < 2; ++it) {
        int g   = it*256 + tid;
        int dT  = g & 63;
        int lch = g >> 6;                  // 0..7
        us8 v;
        #pragma unroll
        for (int j = 0; j < 8; j++)
            v[j] = t2[(lch*8 + j)*68 + dT];
        size_t gr = ((size_t)b*(SEQ>>3) + (l0>>3) + lch)*DINNER + d0 + dT;
        *(us8*)&xsT[gr*8] = v;
    }
}

// ========== chunked selective scan, one d-channel per lane ==========
// grid: B_SZ * NCHUNK * 8 blocks (512); dg = blk&7, c = (blk>>3)&(NCHUNK-1), b = blk>>8
// d = dg*256 + tid. deT/xsT in packed layout [b][l/8][DINNER][8] -> fully coalesced
// us8 loads (consecutive lanes = consecutive 16B). B/C rows wave-uniform (scalar pipe).
// Fast path (A_log = log(arange(1..16)) broadcast, verified per-wave):
// exp(de*A[n]) = r^(n+1), r = exp2(-de*LOG2E), log-depth power chain.
__global__ __launch_bounds__(256)
void scan_pass1(const unsigned short* __restrict__ deT,
                const unsigned short* __restrict__ xsT,
                const float* __restrict__ dbc,
                const float* __restrict__ A_log,
                float* __restrict__ Bc, float* __restrict__ sde)
{
    const int tid = threadIdx.x;
    const int blk = blockIdx.x;
    const int dg  = blk & 7;
    const int c   = (blk >> 3) & (NCHUNK-1);
    const int b   = blk >> 8;
    const int d   = dg*256 + tid;

    float An[16];
    bool okv = true;
    #pragma unroll
    for (int n = 0; n < 16; n++) {
        An[n] = -__expf(A_log[d*DSTATE + n]) * LOG2E;
        okv = okv && (fabsf(An[n] + (float)(n+1)*LOG2E) < 2e-3f*(float)(n+1));
    }
    const bool fast = __all((int)okv);

    const us8* de8p = (const us8*)deT;
    const us8* u8p  = (const us8*)xsT;
    const float* brow = dbc + (size_t)b*SEQ*96 + (size_t)(c*TCHUNK)*96 + DTRANK;

    float h[16];
    #pragma unroll
    for (int n = 0; n < 16; n++) h[n] = 0.f;
    float s = 0.f;

    if (fast) {
        for (int t8 = 0; t8 < TCHUNK/8; ++t8) {
            size_t gi = ((size_t)b*(SEQ>>3) + c*(TCHUNK>>3) + t8)*(size_t)DINNER + d;
            us8 de8 = de8p[gi];
            us8 u8  = u8p[gi];
            #pragma unroll
            for (int j2 = 0; j2 < 8; j2++) {
                const float* br = brow + (size_t)(t8*8 + j2)*96;   // wave-uniform
                float de = b2f(de8[j2]);
                float du = de * b2f(u8[j2]);
                float r  = exp2f(de * (-LOG2E));
                float e[16];
                pow_chain(r, e);
                #pragma unroll
                for (int n = 0; n < 16; n++)
                    h[n] = e[n]*h[n] + du*br[n];
                s += de;
            }
        }
    } else {
        for (int t8 = 0; t8 < TCHUNK/8; ++t8) {
            size_t gi = ((size_t)b*(SEQ>>3) + c*(TCHUNK>>3) + t8)*(size_t)DINNER + d;
            us8 de8 = de8p[gi];
            us8 u8  = u8p[gi];
            #pragma unroll
            for (int j2 = 0; j2 < 8; j2++) {
                const float* br = brow + (size_t)(t8*8 + j2)*96;
                float de = b2f(de8[j2]);
                float du = de * b2f(u8[j2]);
                #pragma unroll
                for (int n = 0; n < 16; n++)
                    h[n] = exp2f(de*An[n])*h[n] + du*br[n];
                s += de;
            }
        }
    }

    size_t ci = (size_t)(b*NCHUNK + c)*DINNER + d;
    #pragma unroll
    for (int n = 0; n < 16; n += 4) {
        float4 v; v.x = h[n]; v.y = h[n+1]; v.z = h[n+2]; v.w = h[n+3];
        *(float4*)&Bc[ci*16 + n] = v;
    }
    sde[ci] = s;
}

__global__ __launch_bounds__(256)
void scan_pass2(float* __restrict__ Bc, const float* __restrict__ sde,
                const float* __restrict__ A_log)
{
    const int tid = threadIdx.x;
    const int n   = tid & 15, dl = tid >> 4;
    const int blk = blockIdx.x;
    const int dg  = blk & 127, b = blk >> 7;
    const int d   = dg*16 + dl;
    const float An = -__expf(A_log[d*DSTATE + n]) * LOG2E;

    float H = 0.f;
    for (int c = 0; c < NCHUNK; ++c) {
        size_t ci = (size_t)(b*NCHUNK + c)*DINNER + d;
        float bc = Bc[ci*16 + n];
        Bc[ci*16 + n] = H;
        H = exp2f(An*sde[ci])*H + bc;
    }
}

// pass3: full recurrence seeded with Hinit, fused gate y = (cc + u*D) * silu(z)
__global__ __launch_bounds__(256)
void scan_pass3(const unsigned short* __restrict__ deT,
                const unsigned short* __restrict__ xsT,
                const float* __restrict__ dbc,
                const float* __restrict__ A_log,
                const float* __restrict__ Dp,
                const float* __restrict__ Hinit,
                const unsigned short* __restrict__ zN,
                __hip_bfloat16* __restrict__ yN)
{
    const int tid = threadIdx.x;
    const int blk = blockIdx.x;
    const int dg  = blk & 7;
    const int c   = (blk >> 3) & (NCHUNK-1);
    const int b   = blk >> 8;
    const int d   = dg*256 + tid;

    float An[16];
    bool okv = true;
    #pragma unroll
    for (int n = 0; n < 16; n++) {
        An[n] = -__expf(A_log[d*DSTATE + n]) * LOG2E;
        okv = okv && (fabsf(An[n] + (float)(n+1)*LOG2E) < 2e-3f*(float)(n+1));
    }
    const bool fast = __all((int)okv);
    const float Dd = Dp[d];

    const us8* de8p = (const us8*)deT;
    const us8* u8p  = (const us8*)xsT;
    size_t baseN = (size_t)b*SEQ*DINNER + d;
    const float* brow = dbc + (size_t)b*SEQ*96 + (size_t)(c*TCHUNK)*96 + DTRANK;

    size_t ci = (size_t)(b*NCHUNK + c)*DINNER + d;
    float h[16];
    #pragma unroll
    for (int n = 0; n < 16; n += 4) {
        float4 v = *(const float4*)&Hinit[ci*16 + n];
        h[n] = v.x; h[n+1] = v.y; h[n+2] = v.z; h[n+3] = v.w;
    }

    if (fast) {
        for (int t8 = 0; t8 < TCHUNK/8; ++t8) {
            size_t gi = ((size_t)b*(SEQ>>3) + c*(TCHUNK>>3) + t8)*(size_t)DINNER + d;
            us8 de8 = de8p[gi];
            us8 u8  = u8p[gi];
            #pragma unroll
            for (int j2 = 0; j2 < 8; j2++) {
                int l = c*TCHUNK + t8*8 + j2;
                const float* br = brow + (size_t)(t8*8 + j2)*96;   // wave-uniform
                float de = b2f(de8[j2]);
                float u  = b2f(u8[j2]);
                float du = de * u;
                float r  = exp2f(de * (-LOG2E));
                float e[16];
                pow_chain(r, e);
                float cc = 0.f;
                #pragma unroll
                for (int n = 0; n < 16; n++) {
                    h[n] = e[n]*h[n] + du*br[n];
                    cc  += h[n]*br[DSTATE + n];
                }
                float zv = silu_f(b2f(zN[baseN + (size_t)l*DINNER]));
                yN[baseN + (size_t)l*DINNER] = __float2bfloat16((cc + u*Dd) * zv);
            }
        }
    } else {
        for (int t8 = 0; t8 < TCHUNK/8; ++t8) {
            size_t gi = ((size_t)b*(SEQ>>3) + c*(TCHUNK>>3) + t8)*(size_t)DINNER + d;
            us8 de8 = de8p[gi];
            us8 u8  = u8p[gi];
            #pragma unroll
            for (int j2 = 0; j2 < 8; j2++) {
                int l = c*TCHUNK + t8*8 + j2;
                const float* br = brow + (size_t)(t8*8 + j2)*96;
                float de = b2f(de8[j2]);
                float u  = b2f(u8[j2]);
                float du = de * u;
                float cc = 0.f;
                #pragma unroll
                for (int n = 0; n < 16; n++) {
                    h[n] = exp2f(de*An[n])*h[n] + du*br[n];
                    cc  += h[n]*br[DSTATE + n];
                }
                float zv = silu_f(b2f(zN[baseN + (size_t)l*DINNER]));
                yN[baseN + (size_t)l*DINNER] = __float2bfloat16((cc + u*Dd) * zv);
            }
        }
    }
}

// ---------- diagnostic fallback ----------
__global__ __launch_bounds__(256)
void zero_out_kernel(float* out, int n) {
    int i = blockIdx.x * 256 + threadIdx.x;
    if (i < n) out[i] = 0.f;
}

extern "C" void kernel_launch(void* const* d_in, const int* in_sizes, int n_in,
                              void* d_out, int out_size, void* d_ws, size_t ws_size,
                              hipStream_t stream) {
    const float* x      = (const float*)d_in[0];
    const float* W_in   = (const float*)d_in[1];
    const float* conv_w = (const float*)d_in[2];
    const float* conv_b = (const float*)d_in[3];
    const float* W_x    = (const float*)d_in[4];
    const float* W_dt   = (const float*)d_in[5];
    const float* b_dt   = (const float*)d_in[6];
    const float* A_log  = (const float*)d_in[7];
    const float* D_par  = (const float*)d_in[8];
    const float* W_out  = (const float*)d_in[9];

    size_t szBig = (size_t)BLROWS * DINNER * 2;                   // 8.39 MB
    size_t szBc  = (size_t)B_SZ * NCHUNK * DINNER * DSTATE * 4;   // 8.39 MB
    size_t need  = 5*szBig                       // xbufN,zbufN,xsN,xsT,deT
                 + (size_t)BLROWS*96*4                        // dbc
                 + (size_t)NSLICE*BLROWS*96*4                 // dbc partials
                 + (size_t)BLROWS*DTRANK*2                    // dtH
                 + szBc + (size_t)B_SZ*NCHUNK*DINNER*4
                 + (size_t)BLROWS*DMODEL*2       // xH
                 + (size_t)2*DINNER*DMODEL*2     // WinH
                 + (size_t)128*DINNER*2          // WxH
                 + (size_t)DINNER*DTRANK*2       // WdtH
                 + (size_t)DMODEL*DINNER*2;      // WoutH   (~83 MB, ws is ~268 MB)

    if (ws_size < need) {
        zero_out_kernel<<<(out_size + 255)/256, 256, 0, stream>>>((float*)d_out, out_size);
        return;
    }

    char* w = (char*)d_ws;
    __hip_bfloat16* xbufN = (__hip_bfloat16*)w;  w += szBig;
    __hip_bfloat16* zbufN = (__hip_bfloat16*)w;  w += szBig;
    __hip_bfloat16* xsN   = (__hip_bfloat16*)w;  w += szBig;   // later y (in-place)
    __hip_bfloat16* xsT   = (__hip_bfloat16*)w;  w += szBig;
    __hip_bfloat16* deT   = (__hip_bfloat16*)w;  w += szBig;
    float*          dbc   = (float*)w;           w += (size_t)BLROWS * 96 * 4;
    float*          dbcP  = (float*)w;           w += (size_t)NSLICE * BLROWS * 96 * 4;
    __hip_bfloat16* dtH   = (__hip_bfloat16*)w;  w += (size_t)BLROWS * DTRANK * 2;
    float*          Bc    = (float*)w;           w += szBc;
    float*          sde   = (float*)w;           w += (size_t)B_SZ * NCHUNK * DINNER * 4;
    __hip_bfloat16* xH    = (__hip_bfloat16*)w;  w += (size_t)BLROWS*DMODEL*2;
    __hip_bfloat16* WinH  = (__hip_bfloat16*)w;  w += (size_t)2*DINNER*DMODEL*2;
    __hip_bfloat16* WxH   = (__hip_bfloat16*)w;  w += (size_t)128*DINNER*2;
    __hip_bfloat16* WdtH  = (__hip_bfloat16*)w;  w += (size_t)DINNER*DTRANK*2;
    __hip_bfloat16* WoutH = (__hip_bfloat16*)w;  w += (size_t)DMODEL*DINNER*2;
    __hip_bfloat16* yN    = xsN;

    // 0) fused init: all casts
    init_kernel<<<GTOT/256, 256, 0, stream>>>(x, W_in, W_x, W_dt, W_out,
        (unsigned short*)xH, (unsigned short*)WinH, (unsigned short*)WxH,
        (unsigned short*)WdtH, (unsigned short*)WoutH);

    // 1) xz = x @ W_in^T -> xbufN | zbufN. 128x128 tiles, 512 blocks (2/CU)
    gemm_tn<128,128,5,false><<<dim3(BLROWS/128, (2*DINNER)/128, 1), 256, 0, stream>>>(
        xH, WinH, BLROWS, 2*DINNER, DMODEL, DMODEL, nullptr, xbufN, zbufN, nullptr);

    // 2) fused conv+silu+transpose: xbufN -> xsN + xsT (packed)
    conv_transpose_kernel<<<dim3(SEQ/64, DINNER/64, B_SZ), 256, 0, stream>>>(
        (const unsigned short*)xbufN, conv_w, conv_b,
        (unsigned short*)xsN, (unsigned short*)xsT);

    // 3) dbc partials = x_ssm @ W_x^T (N=96, split-K=16, plain stores; 512 blocks)
    //    then fused reduce + dt cvt
    gemm_tn<128,64,9,true><<<dim3(BLROWS/128, 2, NSLICE), 256, 0, stream>>>(
        xsN, WxH, BLROWS, 96, DINNER, DINNER/NSLICE, dbcP, nullptr, nullptr, nullptr);
    dbc_reduce_kernel<<<BLROWS/2, 192, 0, stream>>>(dbcP, dbc, dtH);

    // 4) delta = softplus(dt @ W_dt^T + b_dt) -> deT (packed) via LDS-transpose epilogue.
    gemm_tn<64,64,8,false><<<dim3(BLROWS/64, DINNER/64, 1), 256, 0, stream>>>(
        dtH, WdtH, BLROWS, DINNER, DTRANK, DTRANK, nullptr, deT, nullptr, b_dt);

    // 5) chunked selective scan, d-per-lane, packed coalesced loads. 512 blocks
    scan_pass1<<<B_SZ*NCHUNK*8, 256, 0, stream>>>((const unsigned short*)deT,
        (const unsigned short*)xsT, dbc, A_log, Bc, sde);
    scan_pass2<<<B_SZ*128, 256, 0, stream>>>(Bc, sde, A_log);
    scan_pass3<<<B_SZ*NCHUNK*8, 256, 0, stream>>>((const unsigned short*)deT,
        (const unsigned short*)xsT, dbc, A_log, D_par, Bc,
        (const unsigned short*)zbufN, yN);

    // 6) out = y @ W_out^T -> d_out. 64x64 tiles -> 512 blocks (2/CU), direct f32 store
    gemm_tn<64,64,9,false><<<dim3(BLROWS/64, DMODEL/64, 1), 256, 0, stream>>>(
        yN, WoutH, BLROWS, DMODEL, DINNER, DINNER, (float*)d_out, nullptr, nullptr, nullptr);
}

// Round 9
// 214.333 us; speedup vs baseline: 1.0096x; 1.0096x over previous
//
#include <hip/hip_runtime.h>
#include <hip/hip_bf16.h>

#define B_SZ   2
#define SEQ    1024
#define DMODEL 1024
#define DINNER 2048
#define DSTATE 16
#define DCONV  4
#define DTRANK 64
#define BLROWS (B_SZ*SEQ)
#define NCHUNK 32
#define TCHUNK (SEQ/NCHUNK) // 32
#define NSLICE 16           // dbc split-K partials
#define LOG2E 1.44269504088896f

using floatx4 = __attribute__((ext_vector_type(4))) float;
using short8  = __attribute__((ext_vector_type(8))) short;
using us8     = __attribute__((ext_vector_type(8))) unsigned short;
using us4     = __attribute__((ext_vector_type(4))) unsigned short;

__device__ __forceinline__ float softplus_f(float x) {
    return fmaxf(x, 0.f) + log1pf(__expf(-fabsf(x)));
}
__device__ __forceinline__ float silu_f(float x) {
    return x / (1.f + __expf(-x));
}
__device__ __forceinline__ short bfs(float x) {
    union { __hip_bfloat16 h; short s; } u;
    u.h = __float2bfloat16(x);
    return u.s;
}
__device__ __forceinline__ float b2f(unsigned short s) {
    union { float f; unsigned u; } x;
    x.u = ((unsigned)s) << 16;
    return x.f;
}
__device__ __forceinline__ void gld16(const void* g, void* l) {
    __builtin_amdgcn_global_load_lds((const __attribute__((address_space(1))) void*)g,
                                     (__attribute__((address_space(3))) void*)l,
                                     16, 0, 0);
}
// counted vmcnt wait (immediate operand via if constexpr dispatch)
template<int N> __device__ __forceinline__ void wait_vm() {
    if constexpr (N == 0) asm volatile("s_waitcnt vmcnt(0)" ::: "memory");
    else if constexpr (N == 1) asm volatile("s_waitcnt vmcnt(1)" ::: "memory");
    else if constexpr (N == 2) asm volatile("s_waitcnt vmcnt(2)" ::: "memory");
    else if constexpr (N == 3) asm volatile("s_waitcnt vmcnt(3)" ::: "memory");
    else                       asm volatile("s_waitcnt vmcnt(4)" ::: "memory");
}
// e[n] = r^(n+1), log-depth (max 4 dependent muls)
__device__ __forceinline__ void pow_chain(float r, float* e) {
    float r2 = r*r, r4 = r2*r2, r8 = r4*r4;
    e[0] = r;      e[1] = r2;     e[2] = r*r2;   e[3] = r4;
    e[4] = r*r4;   e[5] = r2*r4;  e[6] = e[2]*r4; e[7] = r8;
    e[8] = r*r8;   e[9] = r2*r8;  e[10] = e[2]*r8; e[11] = r4*r8;
    e[12] = e[4]*r8; e[13] = e[5]*r8; e[14] = e[6]*r8; e[15] = r8*r8;
}
__device__ __forceinline__ void cast8(const float* src, unsigned short* dst, int i) {
    const float* p = src + (size_t)i*8;
    float4 a = *(const float4*)p, b = *(const float4*)(p+4);
    us8 o;
    o[0]=(unsigned short)bfs(a.x); o[1]=(unsigned short)bfs(a.y);
    o[2]=(unsigned short)bfs(a.z); o[3]=(unsigned short)bfs(a.w);
    o[4]=(unsigned short)bfs(b.x); o[5]=(unsigned short)bfs(b.y);
    o[6]=(unsigned short)bfs(b.z); o[7]=(unsigned short)bfs(b.w);
    *(us8*)(dst + (size_t)i*8) = o;
}

// ---------- fused init: 5 casts, range-partitioned ----------
#define G0 (BLROWS*DMODEL/8)       // x cast
#define G1 (2*DINNER*DMODEL/8)     // W_in cast
#define G2 (96*DINNER/8)           // W_x cast
#define G3 (DINNER*DTRANK/8)       // W_dt cast
#define G4 (DMODEL*DINNER/8)       // W_out cast
#define GTOT (G0+G1+G2+G3+G4)
__global__ __launch_bounds__(256)
void init_kernel(const float* __restrict__ x, const float* __restrict__ W_in,
                 const float* __restrict__ W_x, const float* __restrict__ W_dt,
                 const float* __restrict__ W_out,
                 unsigned short* xH, unsigned short* WinH, unsigned short* WxH,
                 unsigned short* WdtH, unsigned short* WoutH)
{
    int i = blockIdx.x*256 + threadIdx.x;
    if (i < G0) { cast8(x, xH, i); return; }            i -= G0;
    if (i < G1) { cast8(W_in, WinH, i); return; }       i -= G1;
    if (i < G2) { cast8(W_x, WxH, i); return; }         i -= G2;
    if (i < G3) { cast8(W_dt, WdtH, i); return; }       i -= G3;
    if (i < G4) { cast8(W_out, WoutH, i); }
}

// ---------- TN MFMA GEMM, counted-vmcnt pipelined K-loop, tile TM x TN, BK=32 ----------
// Prefetch stays in flight across barriers (T4): s_waitcnt vmcnt(VM) + raw s_barrier
// instead of __syncthreads' full vmcnt(0) drain. VM = loads/wave = AG+EB (staging rows
// clamped under NGUARD so every wave issues the same count).
// EPI: 5 = split col<DINNER -> outH else outH2 (ld DINNER), bf16
//      8 = softplus(v + bias[col]) -> bf16 packed layout [b][l/8][DINNER][8] (coalesced)
//      9 = plain f32 store to outF + blockIdx.z*M*N (partials / direct out)
template<int TM, int TN, int EPI, bool NGUARD>
__global__ __launch_bounds__(256)
void gemm_tn(const __hip_bfloat16* __restrict__ Ag, const __hip_bfloat16* __restrict__ Bg,
             int M, int N, int K, int kslice,
             float* __restrict__ outF,
             __hip_bfloat16* __restrict__ outH,
             __hip_bfloat16* __restrict__ outH2,
             const float* __restrict__ bias)
{
    constexpr int AG  = TM/64;        // A-tile 64-row stage groups
    constexpr int EB  = TN/64;        // B-tile 64-row stage groups
    constexpr int MF  = TM/32;        // frag-rows per wave
    constexpr int NF  = TN/32;        // frag-cols per wave
    constexpr int VM  = AG + EB;      // gld16 per wave per stage
    constexpr int SM_SZ = 2*TM*32 + 2*TN*32;
    __shared__ short smem[SM_SZ];
    auto As = (short(*)[TM*32])smem;
    auto Bs = (short(*)[TN*32])(smem + 2*TM*32);

    const int tid  = threadIdx.x;
    const int lane = tid & 63, wave = tid >> 6;
    const int bm0  = blockIdx.x * TM;
    const int bn0  = blockIdx.y * TN;
    const int kbeg = blockIdx.z * kslice;
    const int kend = kbeg + kslice;
    const int wrow = (wave >> 1) * (TM/2), wcol = (wave & 1) * (TN/2);
    const int lrow = lane & 15, quad = lane >> 4;

    const int srow = wave*16 + (lane >> 2);
    const int scol = (lane & 3) * 8;

    // B staging rows clamped under NGUARD: all waves issue VM loads (uniform vmcnt);
    // OOB columns compute garbage that the epilogue discards.
    int br0 = bn0 + srow;
    int br1 = bn0 + srow + 64;
    if (NGUARD) { br0 = min(br0, N-1); br1 = min(br1, N-1); }

    const __hip_bfloat16* ga0 = Ag + (size_t)(bm0 + srow)*K      + scol;
    const __hip_bfloat16* ga1 = (AG > 1) ? Ag + (size_t)(bm0 + srow + 64)*K + scol : nullptr;
    const __hip_bfloat16* gb0 = Bg + (size_t)br0*K + scol;
    const __hip_bfloat16* gb1 = (EB > 1) ? Bg + (size_t)br1*K + scol : nullptr;

    auto stage = [&](int c, int k0) {
        gld16(ga0 + k0, &As[c][(wave*16)*32]);
        if (AG > 1) gld16(ga1 + k0, &As[c][(wave*16 + 64)*32]);
        gld16(gb0 + k0, &Bs[c][(wave*16)*32]);
        if (EB > 1) gld16(gb1 + k0, &Bs[c][(wave*16 + 64)*32]);
    };

    floatx4 acc[MF][NF] = {};

    // prologue: stage first tile, full drain once
    stage(0, kbeg);
    __syncthreads();
    int cur = 0;
    for (int k0 = kbeg; k0 < kend; k0 += 32) {
        const bool pf = (k0 + 32 < kend);
        if (pf) stage(cur ^ 1, k0 + 32);   // next-tile loads in flight
        if (pf) wait_vm<VM>(); else wait_vm<0>();   // my tile-t loads done; prefetch stays
        __builtin_amdgcn_s_barrier();               // all waves' tile-t loads landed
        short8 af[MF], bf[NF];
        #pragma unroll
        for (int i = 0; i < MF; i++)
            af[i] = *(const short8*)&As[cur][(wrow + i*16 + lrow)*32 + quad*8];
        #pragma unroll
        for (int j = 0; j < NF; j++)
            bf[j] = *(const short8*)&Bs[cur][(wcol + j*16 + lrow)*32 + quad*8];
        #pragma unroll
        for (int i = 0; i < MF; i++)
            #pragma unroll
            for (int j = 0; j < NF; j++)
                acc[i][j] = __builtin_amdgcn_mfma_f32_16x16x32_bf16(af[i], bf[j], acc[i][j], 0, 0, 0);
        __builtin_amdgcn_s_barrier();               // reads retired before next stage overwrites
        cur ^= 1;
    }

    const int rq = quad * 4;
    if constexpr (EPI == 8) {
        // softplus -> bf16 into LDS transpose buffer t[TN][TM+8], then write
        // packed layout [b][l/8][DINNER][8]: granule (lchunk, d) = 16B, coalesced.
        constexpr int TSTR = TM + 8;               // row stride 144B (16B multiple)
        static_assert(TN*TSTR <= SM_SZ, "transpose buffer fits");
        short* t = smem;
        __syncthreads();
        #pragma unroll
        for (int i = 0; i < MF; i++) {
            #pragma unroll
            for (int j = 0; j < NF; j++) {
                int cl = wcol + j*16 + lrow;       // local d
                int rl = wrow + i*16 + rq;         // local l (us4-aligned)
                us4 pk;
                #pragma unroll
                for (int r = 0; r < 4; r++)
                    pk[r] = (unsigned short)bfs(softplus_f(acc[i][j][r] + bias[bn0 + cl]));
                *(us4*)&t[cl*TSTR + rl] = pk;
            }
        }
        __syncthreads();
        const int bb = bm0 >> 10, lb = bm0 & (SEQ-1);
        constexpr int NGR  = (TM/8)*TN;            // granules in tile
        constexpr int ITER = NGR/256;
        #pragma unroll
        for (int it = 0; it < ITER; ++it) {
            int g   = it*256 + tid;
            int dd  = g % TN;                      // consecutive lanes -> consecutive d
            int lch = g / TN;
            us8 v = *(const us8*)&t[dd*TSTR + lch*8];
            size_t gr = ((size_t)bb*(SEQ>>3) + (lb>>3) + lch)*DINNER + (bn0 + dd);
            *(us8*)((unsigned short*)outH + gr*8) = v;
        }
    } else {
        #pragma unroll
        for (int i = 0; i < MF; i++) {
            #pragma unroll
            for (int j = 0; j < NF; j++) {
                int col = bn0 + wcol + j*16 + lrow;
                if (NGUARD && col >= N) continue;
                #pragma unroll
                for (int r = 0; r < 4; r++) {
                    int row = bm0 + wrow + i*16 + rq + r;
                    float v = acc[i][j][r];
                    if constexpr (EPI == 5) {
                        if (col < DINNER)
                            outH[(size_t)row*DINNER + col] = __float2bfloat16(v);
                        else
                            outH2[(size_t)row*DINNER + (col - DINNER)] = __float2bfloat16(v);
                    } else if constexpr (EPI == 9) {
                        outF[(size_t)blockIdx.z*M*N + (size_t)row*N + col] = v;
                    }
                }
            }
        }
    }
}

// ---------- dbc split-K reduce + dt cvt (fused) ----------
__global__ __launch_bounds__(192)
void dbc_reduce_kernel(const float* __restrict__ part, float* __restrict__ dbc,
                       __hip_bfloat16* __restrict__ dtH)
{
    const int tid = threadIdx.x;
    const int r2  = (tid >= 96) ? 1 : 0;
    const int col = tid - 96*r2;
    const int row = blockIdx.x*2 + r2;
    const size_t idx = (size_t)row*96 + col;
    float s = 0.f;
    #pragma unroll
    for (int z = 0; z < NSLICE; z++)
        s += part[(size_t)z*(BLROWS*96) + idx];
    dbc[idx] = s;
    if (col < DTRANK)
        dtH[(size_t)row*DTRANK + col] = __float2bfloat16(s);
}

// ---------- fused conv+silu+transpose: xbufN -> xsN (normal) + xsT (packed) ----------
__global__ __launch_bounds__(256)
void conv_transpose_kernel(const unsigned short* __restrict__ xbufN,
                           const float* __restrict__ cw,
                           const float* __restrict__ cb,
                           unsigned short* __restrict__ xsN,
                           unsigned short* __restrict__ xsT)
{
    __shared__ unsigned short t[67*68];    // rows l0-3 .. l0+63
    __shared__ unsigned short t2[64*68];
    const int tid = threadIdx.x;
    const int l0 = blockIdx.x * 64, d0 = blockIdx.y * 64, b = blockIdx.z;

    const int lc4 = (tid & 15) * 4;
    for (int r = tid >> 4; r < 67; r += 16) {
        int lg = l0 - 3 + r;
        us4 v = {0,0,0,0};
        if (lg >= 0)
            v = *(const us4*)&xbufN[((size_t)(b*SEQ + lg))*DINNER + d0 + lc4];
        *(us4*)&t[r*68 + lc4] = v;
    }
    __syncthreads();

    const int dd = tid & 63;
    float4 w4 = *(const float4*)&cw[(d0 + dd)*4];
    float  bb = cb[d0 + dd];
    #pragma unroll 4
    for (int rr = tid >> 6; rr < 64; rr += 4) {
        float acc = bb;
        acc += w4.x * b2f(t[(rr+0)*68 + dd]);
        acc += w4.y * b2f(t[(rr+1)*68 + dd]);
        acc += w4.z * b2f(t[(rr+2)*68 + dd]);
        acc += w4.w * b2f(t[(rr+3)*68 + dd]);
        unsigned short h = (unsigned short)bfs(silu_f(acc));
        t2[rr*68 + dd] = h;
        xsN[((size_t)(b*SEQ + l0 + rr))*DINNER + d0 + dd] = h;
    }
    __syncthreads();

    // packed layout [b][l/8][DINNER][8]: granule (lchunk, d), coalesced us8 writes
    #pragma unroll
    for (int it = 0; it < 2; ++it) {
        int g   = it*256 + tid;
        int dT  = g & 63;
        int lch = g >> 6;                  // 0..7
        us8 v;
        #pragma unroll
        for (int j = 0; j < 8; j++)
            v[j] = t2[(lch*8 + j)*68 + dT];
        size_t gr = ((size_t)b*(SEQ>>3) + (l0>>3) + lch)*DINNER + d0 + dT;
        *(us8*)&xsT[gr*8] = v;
    }
}

// ========== chunked selective scan, one d-channel per lane ==========
// grid: B_SZ * NCHUNK * 8 blocks (512); dg = blk&7, c = (blk>>3)&(NCHUNK-1), b = blk>>8
// d = dg*256 + tid. deT/xsT in packed layout [b][l/8][DINNER][8] -> fully coalesced
// us8 loads (consecutive lanes = consecutive 16B). B/C rows wave-uniform (scalar pipe).
// Fast path (A_log = log(arange(1..16)) broadcast, verified per-wave):
// exp(de*A[n]) = r^(n+1), r = exp2(-de*LOG2E), log-depth power chain.
__global__ __launch_bounds__(256)
void scan_pass1(const unsigned short* __restrict__ deT,
                const unsigned short* __restrict__ xsT,
                const float* __restrict__ dbc,
                const float* __restrict__ A_log,
                float* __restrict__ Bc, float* __restrict__ sde)
{
    const int tid = threadIdx.x;
    const int blk = blockIdx.x;
    const int dg  = blk & 7;
    const int c   = (blk >> 3) & (NCHUNK-1);
    const int b   = blk >> 8;
    const int d   = dg*256 + tid;

    float An[16];
    bool okv = true;
    #pragma unroll
    for (int n = 0; n < 16; n++) {
        An[n] = -__expf(A_log[d*DSTATE + n]) * LOG2E;
        okv = okv && (fabsf(An[n] + (float)(n+1)*LOG2E) < 2e-3f*(float)(n+1));
    }
    const bool fast = __all((int)okv);

    const us8* de8p = (const us8*)deT;
    const us8* u8p  = (const us8*)xsT;
    const float* brow = dbc + (size_t)b*SEQ*96 + (size_t)(c*TCHUNK)*96 + DTRANK;

    float h[16];
    #pragma unroll
    for (int n = 0; n < 16; n++) h[n] = 0.f;
    float s = 0.f;

    if (fast) {
        for (int t8 = 0; t8 < TCHUNK/8; ++t8) {
            size_t gi = ((size_t)b*(SEQ>>3) + c*(TCHUNK>>3) + t8)*(size_t)DINNER + d;
            us8 de8 = de8p[gi];
            us8 u8  = u8p[gi];
            #pragma unroll
            for (int j2 = 0; j2 < 8; j2++) {
                const float* br = brow + (size_t)(t8*8 + j2)*96;   // wave-uniform
                float de = b2f(de8[j2]);
                float du = de * b2f(u8[j2]);
                float r  = exp2f(de * (-LOG2E));
                float e[16];
                pow_chain(r, e);
                #pragma unroll
                for (int n = 0; n < 16; n++)
                    h[n] = e[n]*h[n] + du*br[n];
                s += de;
            }
        }
    } else {
        for (int t8 = 0; t8 < TCHUNK/8; ++t8) {
            size_t gi = ((size_t)b*(SEQ>>3) + c*(TCHUNK>>3) + t8)*(size_t)DINNER + d;
            us8 de8 = de8p[gi];
            us8 u8  = u8p[gi];
            #pragma unroll
            for (int j2 = 0; j2 < 8; j2++) {
                const float* br = brow + (size_t)(t8*8 + j2)*96;
                float de = b2f(de8[j2]);
                float du = de * b2f(u8[j2]);
                #pragma unroll
                for (int n = 0; n < 16; n++)
                    h[n] = exp2f(de*An[n])*h[n] + du*br[n];
                s += de;
            }
        }
    }

    size_t ci = (size_t)(b*NCHUNK + c)*DINNER + d;
    #pragma unroll
    for (int n = 0; n < 16; n += 4) {
        float4 v; v.x = h[n]; v.y = h[n+1]; v.z = h[n+2]; v.w = h[n+3];
        *(float4*)&Bc[ci*16 + n] = v;
    }
    sde[ci] = s;
}

__global__ __launch_bounds__(256)
void scan_pass2(float* __restrict__ Bc, const float* __restrict__ sde,
                const float* __restrict__ A_log)
{
    const int tid = threadIdx.x;
    const int n   = tid & 15, dl = tid >> 4;
    const int blk = blockIdx.x;
    const int dg  = blk & 127, b = blk >> 7;
    const int d   = dg*16 + dl;
    const float An = -__expf(A_log[d*DSTATE + n]) * LOG2E;

    float H = 0.f;
    for (int c = 0; c < NCHUNK; ++c) {
        size_t ci = (size_t)(b*NCHUNK + c)*DINNER + d;
        float bc = Bc[ci*16 + n];
        Bc[ci*16 + n] = H;
        H = exp2f(An*sde[ci])*H + bc;
    }
}

// pass3: full recurrence seeded with Hinit, fused gate y = (cc + u*D) * silu(z)
__global__ __launch_bounds__(256)
void scan_pass3(const unsigned short* __restrict__ deT,
                const unsigned short* __restrict__ xsT,
                const float* __restrict__ dbc,
                const float* __restrict__ A_log,
                const float* __restrict__ Dp,
                const float* __restrict__ Hinit,
                const unsigned short* __restrict__ zN,
                __hip_bfloat16* __restrict__ yN)
{
    const int tid = threadIdx.x;
    const int blk = blockIdx.x;
    const int dg  = blk & 7;
    const int c   = (blk >> 3) & (NCHUNK-1);
    const int b   = blk >> 8;
    const int d   = dg*256 + tid;

    float An[16];
    bool okv = true;
    #pragma unroll
    for (int n = 0; n < 16; n++) {
        An[n] = -__expf(A_log[d*DSTATE + n]) * LOG2E;
        okv = okv && (fabsf(An[n] + (float)(n+1)*LOG2E) < 2e-3f*(float)(n+1));
    }
    const bool fast = __all((int)okv);
    const float Dd = Dp[d];

    const us8* de8p = (const us8*)deT;
    const us8* u8p  = (const us8*)xsT;
    size_t baseN = (size_t)b*SEQ*DINNER + d;
    const float* brow = dbc + (size_t)b*SEQ*96 + (size_t)(c*TCHUNK)*96 + DTRANK;

    size_t ci = (size_t)(b*NCHUNK + c)*DINNER + d;
    float h[16];
    #pragma unroll
    for (int n = 0; n < 16; n += 4) {
        float4 v = *(const float4*)&Hinit[ci*16 + n];
        h[n] = v.x; h[n+1] = v.y; h[n+2] = v.z; h[n+3] = v.w;
    }

    if (fast) {
        for (int t8 = 0; t8 < TCHUNK/8; ++t8) {
            size_t gi = ((size_t)b*(SEQ>>3) + c*(TCHUNK>>3) + t8)*(size_t)DINNER + d;
            us8 de8 = de8p[gi];
            us8 u8  = u8p[gi];
            #pragma unroll
            for (int j2 = 0; j2 < 8; j2++) {
                int l = c*TCHUNK + t8*8 + j2;
                const float* br = brow + (size_t)(t8*8 + j2)*96;   // wave-uniform
                float de = b2f(de8[j2]);
                float u  = b2f(u8[j2]);
                float du = de * u;
                float r  = exp2f(de * (-LOG2E));
                float e[16];
                pow_chain(r, e);
                float cc = 0.f;
                #pragma unroll
                for (int n = 0; n < 16; n++) {
                    h[n] = e[n]*h[n] + du*br[n];
                    cc  += h[n]*br[DSTATE + n];
                }
                float zv = silu_f(b2f(zN[baseN + (size_t)l*DINNER]));
                yN[baseN + (size_t)l*DINNER] = __float2bfloat16((cc + u*Dd) * zv);
            }
        }
    } else {
        for (int t8 = 0; t8 < TCHUNK/8; ++t8) {
            size_t gi = ((size_t)b*(SEQ>>3) + c*(TCHUNK>>3) + t8)*(size_t)DINNER + d;
            us8 de8 = de8p[gi];
            us8 u8  = u8p[gi];
            #pragma unroll
            for (int j2 = 0; j2 < 8; j2++) {
                int l = c*TCHUNK + t8*8 + j2;
                const float* br = brow + (size_t)(t8*8 + j2)*96;
                float de = b2f(de8[j2]);
                float u  = b2f(u8[j2]);
                float du = de * u;
                float cc = 0.f;
                #pragma unroll
                for (int n = 0; n < 16; n++) {
                    h[n] = exp2f(de*An[n])*h[n] + du*br[n];
                    cc  += h[n]*br[DSTATE + n];
                }
                float zv = silu_f(b2f(zN[baseN + (size_t)l*DINNER]));
                yN[baseN + (size_t)l*DINNER] = __float2bfloat16((cc + u*Dd) * zv);
            }
        }
    }
}

// ---------- diagnostic fallback ----------
__global__ __launch_bounds__(256)
void zero_out_kernel(float* out, int n) {
    int i = blockIdx.x * 256 + threadIdx.x;
    if (i < n) out[i] = 0.f;
}

extern "C" void kernel_launch(void* const* d_in, const int* in_sizes, int n_in,
                              void* d_out, int out_size, void* d_ws, size_t ws_size,
                              hipStream_t stream) {
    const float* x      = (const float*)d_in[0];
    const float* W_in   = (const float*)d_in[1];
    const float* conv_w = (const float*)d_in[2];
    const float* conv_b = (const float*)d_in[3];
    const float* W_x    = (const float*)d_in[4];
    const float* W_dt   = (const float*)d_in[5];
    const float* b_dt   = (const float*)d_in[6];
    const float* A_log  = (const float*)d_in[7];
    const float* D_par  = (const float*)d_in[8];
    const float* W_out  = (const float*)d_in[9];

    size_t szBig = (size_t)BLROWS * DINNER * 2;                   // 8.39 MB
    size_t szBc  = (size_t)B_SZ * NCHUNK * DINNER * DSTATE * 4;   // 8.39 MB
    size_t need  = 5*szBig                       // xbufN,zbufN,xsN,xsT,deT
                 + (size_t)BLROWS*96*4                        // dbc
                 + (size_t)NSLICE*BLROWS*96*4                 // dbc partials
                 + (size_t)BLROWS*DTRANK*2                    // dtH
                 + szBc + (size_t)B_SZ*NCHUNK*DINNER*4
                 + (size_t)BLROWS*DMODEL*2       // xH
                 + (size_t)2*DINNER*DMODEL*2     // WinH
                 + (size_t)128*DINNER*2          // WxH
                 + (size_t)DINNER*DTRANK*2       // WdtH
                 + (size_t)DMODEL*DINNER*2;      // WoutH   (~83 MB, ws is ~268 MB)

    if (ws_size < need) {
        zero_out_kernel<<<(out_size + 255)/256, 256, 0, stream>>>((float*)d_out, out_size);
        return;
    }

    char* w = (char*)d_ws;
    __hip_bfloat16* xbufN = (__hip_bfloat16*)w;  w += szBig;
    __hip_bfloat16* zbufN = (__hip_bfloat16*)w;  w += szBig;
    __hip_bfloat16* xsN   = (__hip_bfloat16*)w;  w += szBig;   // later y (in-place)
    __hip_bfloat16* xsT   = (__hip_bfloat16*)w;  w += szBig;
    __hip_bfloat16* deT   = (__hip_bfloat16*)w;  w += szBig;
    float*          dbc   = (float*)w;           w += (size_t)BLROWS * 96 * 4;
    float*          dbcP  = (float*)w;           w += (size_t)NSLICE * BLROWS * 96 * 4;
    __hip_bfloat16* dtH   = (__hip_bfloat16*)w;  w += (size_t)BLROWS * DTRANK * 2;
    float*          Bc    = (float*)w;           w += szBc;
    float*          sde   = (float*)w;           w += (size_t)B_SZ * NCHUNK * DINNER * 4;
    __hip_bfloat16* xH    = (__hip_bfloat16*)w;  w += (size_t)BLROWS*DMODEL*2;
    __hip_bfloat16* WinH  = (__hip_bfloat16*)w;  w += (size_t)2*DINNER*DMODEL*2;
    __hip_bfloat16* WxH   = (__hip_bfloat16*)w;  w += (size_t)128*DINNER*2;
    __hip_bfloat16* WdtH  = (__hip_bfloat16*)w;  w += (size_t)DINNER*DTRANK*2;
    __hip_bfloat16* WoutH = (__hip_bfloat16*)w;  w += (size_t)DMODEL*DINNER*2;
    __hip_bfloat16* yN    = xsN;

    // 0) fused init: all casts
    init_kernel<<<GTOT/256, 256, 0, stream>>>(x, W_in, W_x, W_dt, W_out,
        (unsigned short*)xH, (unsigned short*)WinH, (unsigned short*)WxH,
        (unsigned short*)WdtH, (unsigned short*)WoutH);

    // 1) xz = x @ W_in^T -> xbufN | zbufN. 128x128 tiles, 512 blocks (2/CU)
    gemm_tn<128,128,5,false><<<dim3(BLROWS/128, (2*DINNER)/128, 1), 256, 0, stream>>>(
        xH, WinH, BLROWS, 2*DINNER, DMODEL, DMODEL, nullptr, xbufN, zbufN, nullptr);

    // 2) fused conv+silu+transpose: xbufN -> xsN + xsT (packed)
    conv_transpose_kernel<<<dim3(SEQ/64, DINNER/64, B_SZ), 256, 0, stream>>>(
        (const unsigned short*)xbufN, conv_w, conv_b,
        (unsigned short*)xsN, (unsigned short*)xsT);

    // 3) dbc partials = x_ssm @ W_x^T (N=96, split-K=16, plain stores; 512 blocks)
    //    then fused reduce + dt cvt
    gemm_tn<128,64,9,true><<<dim3(BLROWS/128, 2, NSLICE), 256, 0, stream>>>(
        xsN, WxH, BLROWS, 96, DINNER, DINNER/NSLICE, dbcP, nullptr, nullptr, nullptr);
    dbc_reduce_kernel<<<BLROWS/2, 192, 0, stream>>>(dbcP, dbc, dtH);

    // 4) delta = softplus(dt @ W_dt^T + b_dt) -> deT (packed) via LDS-transpose epilogue.
    gemm_tn<64,64,8,false><<<dim3(BLROWS/64, DINNER/64, 1), 256, 0, stream>>>(
        dtH, WdtH, BLROWS, DINNER, DTRANK, DTRANK, nullptr, deT, nullptr, b_dt);

    // 5) chunked selective scan, d-per-lane, packed coalesced loads. 512 blocks
    scan_pass1<<<B_SZ*NCHUNK*8, 256, 0, stream>>>((const unsigned short*)deT,
        (const unsigned short*)xsT, dbc, A_log, Bc, sde);
    scan_pass2<<<B_SZ*128, 256, 0, stream>>>(Bc, sde, A_log);
    scan_pass3<<<B_SZ*NCHUNK*8, 256, 0, stream>>>((const unsigned short*)deT,
        (const unsigned short*)xsT, dbc, A_log, D_par, Bc,
        (const unsigned short*)zbufN, yN);

    // 6) out = y @ W_out^T -> d_out. 64x64 tiles -> 512 blocks (2/CU), direct f32 store
    gemm_tn<64,64,9,false><<<dim3(BLROWS/64, DMODEL/64, 1), 256, 0, stream>>>(
        yN, WoutH, BLROWS, DMODEL, DINNER, DINNER, (float*)d_out, nullptr, nullptr, nullptr);
}

// Round 10
// 211.921 us; speedup vs baseline: 1.0211x; 1.0114x over previous
//
#include <hip/hip_runtime.h>
#include <hip/hip_bf16.h>

#define B_SZ   2
#define SEQ    1024
#define DMODEL 1024
#define DINNER 2048
#define DSTATE 16
#define DCONV  4
#define DTRANK 64
#define BLROWS (B_SZ*SEQ)
#define NCHUNK 32
#define TCHUNK (SEQ/NCHUNK) // 32
#define NSLICE 16           // dbc split-K partials
#define LOG2E 1.44269504088896f

using floatx4 = __attribute__((ext_vector_type(4))) float;
using short8  = __attribute__((ext_vector_type(8))) short;
using us8     = __attribute__((ext_vector_type(8))) unsigned short;
using us4     = __attribute__((ext_vector_type(4))) unsigned short;

__device__ __forceinline__ float softplus_f(float x) {
    return fmaxf(x, 0.f) + log1pf(__expf(-fabsf(x)));
}
__device__ __forceinline__ float silu_f(float x) {
    return x / (1.f + __expf(-x));
}
__device__ __forceinline__ short bfs(float x) {
    union { __hip_bfloat16 h; short s; } u;
    u.h = __float2bfloat16(x);
    return u.s;
}
__device__ __forceinline__ float b2f(unsigned short s) {
    union { float f; unsigned u; } x;
    x.u = ((unsigned)s) << 16;
    return x.f;
}
__device__ __forceinline__ void gld16(const void* g, void* l) {
    __builtin_amdgcn_global_load_lds((const __attribute__((address_space(1))) void*)g,
                                     (__attribute__((address_space(3))) void*)l,
                                     16, 0, 0);
}
// counted vmcnt wait (immediate operand via if constexpr dispatch)
template<int N> __device__ __forceinline__ void wait_vm() {
    if constexpr (N == 0) asm volatile("s_waitcnt vmcnt(0)" ::: "memory");
    else if constexpr (N == 1) asm volatile("s_waitcnt vmcnt(1)" ::: "memory");
    else if constexpr (N == 2) asm volatile("s_waitcnt vmcnt(2)" ::: "memory");
    else if constexpr (N == 3) asm volatile("s_waitcnt vmcnt(3)" ::: "memory");
    else                       asm volatile("s_waitcnt vmcnt(4)" ::: "memory");
}
// e[n] = r^(n+1), log-depth (max 4 dependent muls)
__device__ __forceinline__ void pow_chain(float r, float* e) {
    float r2 = r*r, r4 = r2*r2, r8 = r4*r4;
    e[0] = r;      e[1] = r2;     e[2] = r*r2;   e[3] = r4;
    e[4] = r*r4;   e[5] = r2*r4;  e[6] = e[2]*r4; e[7] = r8;
    e[8] = r*r8;   e[9] = r2*r8;  e[10] = e[2]*r8; e[11] = r4*r8;
    e[12] = e[4]*r8; e[13] = e[5]*r8; e[14] = e[6]*r8; e[15] = r8*r8;
}
__device__ __forceinline__ void cast8(const float* src, unsigned short* dst, int i) {
    const float* p = src + (size_t)i*8;
    float4 a = *(const float4*)p, b = *(const float4*)(p+4);
    us8 o;
    o[0]=(unsigned short)bfs(a.x); o[1]=(unsigned short)bfs(a.y);
    o[2]=(unsigned short)bfs(a.z); o[3]=(unsigned short)bfs(a.w);
    o[4]=(unsigned short)bfs(b.x); o[5]=(unsigned short)bfs(b.y);
    o[6]=(unsigned short)bfs(b.z); o[7]=(unsigned short)bfs(b.w);
    *(us8*)(dst + (size_t)i*8) = o;
}

// ---------- fused init: 5 casts, range-partitioned ----------
#define G0 (BLROWS*DMODEL/8)       // x cast
#define G1 (2*DINNER*DMODEL/8)     // W_in cast
#define G2 (96*DINNER/8)           // W_x cast
#define G3 (DINNER*DTRANK/8)       // W_dt cast
#define G4 (DMODEL*DINNER/8)       // W_out cast
#define GTOT (G0+G1+G2+G3+G4)
__global__ __launch_bounds__(256)
void init_kernel(const float* __restrict__ x, const float* __restrict__ W_in,
                 const float* __restrict__ W_x, const float* __restrict__ W_dt,
                 const float* __restrict__ W_out,
                 unsigned short* xH, unsigned short* WinH, unsigned short* WxH,
                 unsigned short* WdtH, unsigned short* WoutH)
{
    int i = blockIdx.x*256 + threadIdx.x;
    if (i < G0) { cast8(x, xH, i); return; }            i -= G0;
    if (i < G1) { cast8(W_in, WinH, i); return; }       i -= G1;
    if (i < G2) { cast8(W_x, WxH, i); return; }         i -= G2;
    if (i < G3) { cast8(W_dt, WdtH, i); return; }       i -= G3;
    if (i < G4) { cast8(W_out, WoutH, i); }
}

// ---------- TN MFMA GEMM, counted-vmcnt pipelined K-loop, tile TM x TN, BK=32 ----------
// SWZ: bijective XCD-chunked block remap (T1): each XCD gets a contiguous run of
// nwg/8 blocks so its private L2 keeps the shared B-panels resident.
// EPI: 5 = split col<DINNER -> outH else outH2 (ld DINNER), bf16
//      8 = softplus(v + bias[col]) -> bf16 packed layout [b][l/8][DINNER][8] (coalesced)
//      9 = plain f32 store to outF + blockIdx.z*M*N (partials / direct out)
template<int TM, int TN, int EPI, bool NGUARD, bool SWZ = false>
__global__ __launch_bounds__(256)
void gemm_tn(const __hip_bfloat16* __restrict__ Ag, const __hip_bfloat16* __restrict__ Bg,
             int M, int N, int K, int kslice,
             float* __restrict__ outF,
             __hip_bfloat16* __restrict__ outH,
             __hip_bfloat16* __restrict__ outH2,
             const float* __restrict__ bias)
{
    constexpr int AG  = TM/64;        // A-tile 64-row stage groups
    constexpr int EB  = TN/64;        // B-tile 64-row stage groups
    constexpr int MF  = TM/32;        // frag-rows per wave
    constexpr int NF  = TN/32;        // frag-cols per wave
    constexpr int VM  = AG + EB;      // gld16 per wave per stage
    constexpr int SM_SZ = 2*TM*32 + 2*TN*32;
    __shared__ short smem[SM_SZ];
    auto As = (short(*)[TM*32])smem;
    auto Bs = (short(*)[TN*32])(smem + 2*TM*32);

    const int tid  = threadIdx.x;
    const int lane = tid & 63, wave = tid >> 6;

    int bxr = blockIdx.x, byr = blockIdx.y;
    if constexpr (SWZ) {
        // bijective XCD-chunked remap (grid.x*grid.y must be a multiple of 8)
        int gx  = gridDim.x;
        int lin = byr*gx + bxr;
        int q   = (gx*gridDim.y) >> 3;
        int swz = (lin & 7)*q + (lin >> 3);
        bxr = swz % gx; byr = swz / gx;
    }
    const int bm0  = bxr * TM;
    const int bn0  = byr * TN;
    const int kbeg = blockIdx.z * kslice;
    const int kend = kbeg + kslice;
    const int wrow = (wave >> 1) * (TM/2), wcol = (wave & 1) * (TN/2);
    const int lrow = lane & 15, quad = lane >> 4;

    const int srow = wave*16 + (lane >> 2);
    const int scol = (lane & 3) * 8;

    // B staging rows clamped under NGUARD: all waves issue VM loads (uniform vmcnt);
    // OOB columns compute garbage that the epilogue discards.
    int br0 = bn0 + srow;
    int br1 = bn0 + srow + 64;
    if (NGUARD) { br0 = min(br0, N-1); br1 = min(br1, N-1); }

    const __hip_bfloat16* ga0 = Ag + (size_t)(bm0 + srow)*K      + scol;
    const __hip_bfloat16* ga1 = (AG > 1) ? Ag + (size_t)(bm0 + srow + 64)*K + scol : nullptr;
    const __hip_bfloat16* gb0 = Bg + (size_t)br0*K + scol;
    const __hip_bfloat16* gb1 = (EB > 1) ? Bg + (size_t)br1*K + scol : nullptr;

    auto stage = [&](int c, int k0) {
        gld16(ga0 + k0, &As[c][(wave*16)*32]);
        if (AG > 1) gld16(ga1 + k0, &As[c][(wave*16 + 64)*32]);
        gld16(gb0 + k0, &Bs[c][(wave*16)*32]);
        if (EB > 1) gld16(gb1 + k0, &Bs[c][(wave*16 + 64)*32]);
    };

    floatx4 acc[MF][NF] = {};

    // prologue: stage first tile, full drain once
    stage(0, kbeg);
    __syncthreads();
    int cur = 0;
    for (int k0 = kbeg; k0 < kend; k0 += 32) {
        const bool pf = (k0 + 32 < kend);
        if (pf) stage(cur ^ 1, k0 + 32);   // next-tile loads in flight
        if (pf) wait_vm<VM>(); else wait_vm<0>();   // my tile-t loads done; prefetch stays
        __builtin_amdgcn_s_barrier();               // all waves' tile-t loads landed
        short8 af[MF], bf[NF];
        #pragma unroll
        for (int i = 0; i < MF; i++)
            af[i] = *(const short8*)&As[cur][(wrow + i*16 + lrow)*32 + quad*8];
        #pragma unroll
        for (int j = 0; j < NF; j++)
            bf[j] = *(const short8*)&Bs[cur][(wcol + j*16 + lrow)*32 + quad*8];
        #pragma unroll
        for (int i = 0; i < MF; i++)
            #pragma unroll
            for (int j = 0; j < NF; j++)
                acc[i][j] = __builtin_amdgcn_mfma_f32_16x16x32_bf16(af[i], bf[j], acc[i][j], 0, 0, 0);
        __builtin_amdgcn_s_barrier();               // reads retired before next stage overwrites
        cur ^= 1;
    }

    const int rq = quad * 4;
    if constexpr (EPI == 8) {
        // softplus -> bf16 into LDS transpose buffer t[TN][TM+8], then write
        // packed layout [b][l/8][DINNER][8]: granule (lchunk, d) = 16B, coalesced.
        constexpr int TSTR = TM + 8;               // row stride 144B (16B multiple)
        static_assert(TN*TSTR <= SM_SZ, "transpose buffer fits");
        short* t = smem;
        __syncthreads();
        #pragma unroll
        for (int i = 0; i < MF; i++) {
            #pragma unroll
            for (int j = 0; j < NF; j++) {
                int cl = wcol + j*16 + lrow;       // local d
                int rl = wrow + i*16 + rq;         // local l (us4-aligned)
                us4 pk;
                #pragma unroll
                for (int r = 0; r < 4; r++)
                    pk[r] = (unsigned short)bfs(softplus_f(acc[i][j][r] + bias[bn0 + cl]));
                *(us4*)&t[cl*TSTR + rl] = pk;
            }
        }
        __syncthreads();
        const int bb = bm0 >> 10, lb = bm0 & (SEQ-1);
        constexpr int NGR  = (TM/8)*TN;            // granules in tile
        constexpr int ITER = NGR/256;
        #pragma unroll
        for (int it = 0; it < ITER; ++it) {
            int g   = it*256 + tid;
            int dd  = g % TN;                      // consecutive lanes -> consecutive d
            int lch = g / TN;
            us8 v = *(const us8*)&t[dd*TSTR + lch*8];
            size_t gr = ((size_t)bb*(SEQ>>3) + (lb>>3) + lch)*DINNER + (bn0 + dd);
            *(us8*)((unsigned short*)outH + gr*8) = v;
        }
    } else {
        #pragma unroll
        for (int i = 0; i < MF; i++) {
            #pragma unroll
            for (int j = 0; j < NF; j++) {
                int col = bn0 + wcol + j*16 + lrow;
                if (NGUARD && col >= N) continue;
                #pragma unroll
                for (int r = 0; r < 4; r++) {
                    int row = bm0 + wrow + i*16 + rq + r;
                    float v = acc[i][j][r];
                    if constexpr (EPI == 5) {
                        if (col < DINNER)
                            outH[(size_t)row*DINNER + col] = __float2bfloat16(v);
                        else
                            outH2[(size_t)row*DINNER + (col - DINNER)] = __float2bfloat16(v);
                    } else if constexpr (EPI == 9) {
                        outF[(size_t)blockIdx.z*M*N + (size_t)row*N + col] = v;
                    }
                }
            }
        }
    }
}

// ---------- dbc split-K reduce + dt cvt (fused) ----------
__global__ __launch_bounds__(192)
void dbc_reduce_kernel(const float* __restrict__ part, float* __restrict__ dbc,
                       __hip_bfloat16* __restrict__ dtH)
{
    const int tid = threadIdx.x;
    const int r2  = (tid >= 96) ? 1 : 0;
    const int col = tid - 96*r2;
    const int row = blockIdx.x*2 + r2;
    const size_t idx = (size_t)row*96 + col;
    float s = 0.f;
    #pragma unroll
    for (int z = 0; z < NSLICE; z++)
        s += part[(size_t)z*(BLROWS*96) + idx];
    dbc[idx] = s;
    if (col < DTRANK)
        dtH[(size_t)row*DTRANK + col] = __float2bfloat16(s);
}

// ---------- fused conv+silu+transpose: xbufN -> xsN (normal) + xsT (packed) ----------
__global__ __launch_bounds__(256)
void conv_transpose_kernel(const unsigned short* __restrict__ xbufN,
                           const float* __restrict__ cw,
                           const float* __restrict__ cb,
                           unsigned short* __restrict__ xsN,
                           unsigned short* __restrict__ xsT)
{
    __shared__ unsigned short t[67*68];    // rows l0-3 .. l0+63
    __shared__ unsigned short t2[64*68];
    const int tid = threadIdx.x;
    const int l0 = blockIdx.x * 64, d0 = blockIdx.y * 64, b = blockIdx.z;

    const int lc4 = (tid & 15) * 4;
    for (int r = tid >> 4; r < 67; r += 16) {
        int lg = l0 - 3 + r;
        us4 v = {0,0,0,0};
        if (lg >= 0)
            v = *(const us4*)&xbufN[((size_t)(b*SEQ + lg))*DINNER + d0 + lc4];
        *(us4*)&t[r*68 + lc4] = v;
    }
    __syncthreads();

    const int dd = tid & 63;
    float4 w4 = *(const float4*)&cw[(d0 + dd)*4];
    float  bb = cb[d0 + dd];
    #pragma unroll 4
    for (int rr = tid >> 6; rr < 64; rr += 4) {
        float acc = bb;
        acc += w4.x * b2f(t[(rr+0)*68 + dd]);
        acc += w4.y * b2f(t[(rr+1)*68 + dd]);
        acc += w4.z * b2f(t[(rr+2)*68 + dd]);
        acc += w4.w * b2f(t[(rr+3)*68 + dd]);
        unsigned short h = (unsigned short)bfs(silu_f(acc));
        t2[rr*68 + dd] = h;
        xsN[((size_t)(b*SEQ + l0 + rr))*DINNER + d0 + dd] = h;
    }
    __syncthreads();

    // packed layout [b][l/8][DINNER][8]: granule (lchunk, d), coalesced us8 writes
    #pragma unroll
    for (int it = 0; it < 2; ++it) {
        int g   = it*256 + tid;
        int dT  = g & 63;
        int lch = g >> 6;                  // 0..7
        us8 v;
        #pragma unroll
        for (int j = 0; j < 8; j++)
            v[j] = t2[(lch*8 + j)*68 + dT];
        size_t gr = ((size_t)b*(SEQ>>3) + (l0>>3) + lch)*DINNER + d0 + dT;
        *(us8*)&xsT[gr*8] = v;
    }
}

// ========== chunked selective scan, one d-channel per lane ==========
// grid: B_SZ * NCHUNK * 8 blocks (512); dg = blk&7, c = (blk>>3)&(NCHUNK-1), b = blk>>8
// d = dg*256 + tid. deT/xsT in packed layout [b][l/8][DINNER][8] -> fully coalesced
// us8 loads (consecutive lanes = consecutive 16B). B/C rows wave-uniform (scalar pipe).
// Fast path (A_log = log(arange(1..16)) broadcast, verified per-wave):
// exp(de*A[n]) = r^(n+1), r = exp2(-de*LOG2E), log-depth power chain.
__global__ __launch_bounds__(256)
void scan_pass1(const unsigned short* __restrict__ deT,
                const unsigned short* __restrict__ xsT,
                const float* __restrict__ dbc,
                const float* __restrict__ A_log,
                float* __restrict__ Bc, float* __restrict__ sde)
{
    const int tid = threadIdx.x;
    const int blk = blockIdx.x;
    const int dg  = blk & 7;
    const int c   = (blk >> 3) & (NCHUNK-1);
    const int b   = blk >> 8;
    const int d   = dg*256 + tid;

    float An[16];
    bool okv = true;
    #pragma unroll
    for (int n = 0; n < 16; n++) {
        An[n] = -__expf(A_log[d*DSTATE + n]) * LOG2E;
        okv = okv && (fabsf(An[n] + (float)(n+1)*LOG2E) < 2e-3f*(float)(n+1));
    }
    const bool fast = __all((int)okv);

    const us8* de8p = (const us8*)deT;
    const us8* u8p  = (const us8*)xsT;
    const float* brow = dbc + (size_t)b*SEQ*96 + (size_t)(c*TCHUNK)*96 + DTRANK;

    float h[16];
    #pragma unroll
    for (int n = 0; n < 16; n++) h[n] = 0.f;
    float s = 0.f;

    if (fast) {
        for (int t8 = 0; t8 < TCHUNK/8; ++t8) {
            size_t gi = ((size_t)b*(SEQ>>3) + c*(TCHUNK>>3) + t8)*(size_t)DINNER + d;
            us8 de8 = de8p[gi];
            us8 u8  = u8p[gi];
            #pragma unroll
            for (int j2 = 0; j2 < 8; j2++) {
                const float* br = brow + (size_t)(t8*8 + j2)*96;   // wave-uniform
                float de = b2f(de8[j2]);
                float du = de * b2f(u8[j2]);
                float r  = exp2f(de * (-LOG2E));
                float e[16];
                pow_chain(r, e);
                #pragma unroll
                for (int n = 0; n < 16; n++)
                    h[n] = e[n]*h[n] + du*br[n];
                s += de;
            }
        }
    } else {
        for (int t8 = 0; t8 < TCHUNK/8; ++t8) {
            size_t gi = ((size_t)b*(SEQ>>3) + c*(TCHUNK>>3) + t8)*(size_t)DINNER + d;
            us8 de8 = de8p[gi];
            us8 u8  = u8p[gi];
            #pragma unroll
            for (int j2 = 0; j2 < 8; j2++) {
                const float* br = brow + (size_t)(t8*8 + j2)*96;
                float de = b2f(de8[j2]);
                float du = de * b2f(u8[j2]);
                #pragma unroll
                for (int n = 0; n < 16; n++)
                    h[n] = exp2f(de*An[n])*h[n] + du*br[n];
                s += de;
            }
        }
    }

    size_t ci = (size_t)(b*NCHUNK + c)*DINNER + d;
    #pragma unroll
    for (int n = 0; n < 16; n += 4) {
        float4 v; v.x = h[n]; v.y = h[n+1]; v.z = h[n+2]; v.w = h[n+3];
        *(float4*)&Bc[ci*16 + n] = v;
    }
    sde[ci] = s;
}

__global__ __launch_bounds__(256)
void scan_pass2(float* __restrict__ Bc, const float* __restrict__ sde,
                const float* __restrict__ A_log)
{
    const int tid = threadIdx.x;
    const int n   = tid & 15, dl = tid >> 4;
    const int blk = blockIdx.x;
    const int dg  = blk & 127, b = blk >> 7;
    const int d   = dg*16 + dl;
    const float An = -__expf(A_log[d*DSTATE + n]) * LOG2E;

    float H = 0.f;
    for (int c = 0; c < NCHUNK; ++c) {
        size_t ci = (size_t)(b*NCHUNK + c)*DINNER + d;
        float bc = Bc[ci*16 + n];
        Bc[ci*16 + n] = H;
        H = exp2f(An*sde[ci])*H + bc;
    }
}

// pass3: full recurrence seeded with Hinit, fused gate y = (cc + u*D) * silu(z)
__global__ __launch_bounds__(256)
void scan_pass3(const unsigned short* __restrict__ deT,
                const unsigned short* __restrict__ xsT,
                const float* __restrict__ dbc,
                const float* __restrict__ A_log,
                const float* __restrict__ Dp,
                const float* __restrict__ Hinit,
                const unsigned short* __restrict__ zN,
                __hip_bfloat16* __restrict__ yN)
{
    const int tid = threadIdx.x;
    const int blk = blockIdx.x;
    const int dg  = blk & 7;
    const int c   = (blk >> 3) & (NCHUNK-1);
    const int b   = blk >> 8;
    const int d   = dg*256 + tid;

    float An[16];
    bool okv = true;
    #pragma unroll
    for (int n = 0; n < 16; n++) {
        An[n] = -__expf(A_log[d*DSTATE + n]) * LOG2E;
        okv = okv && (fabsf(An[n] + (float)(n+1)*LOG2E) < 2e-3f*(float)(n+1));
    }
    const bool fast = __all((int)okv);
    const float Dd = Dp[d];

    const us8* de8p = (const us8*)deT;
    const us8* u8p  = (const us8*)xsT;
    size_t baseN = (size_t)b*SEQ*DINNER + d;
    const float* brow = dbc + (size_t)b*SEQ*96 + (size_t)(c*TCHUNK)*96 + DTRANK;

    size_t ci = (size_t)(b*NCHUNK + c)*DINNER + d;
    float h[16];
    #pragma unroll
    for (int n = 0; n < 16; n += 4) {
        float4 v = *(const float4*)&Hinit[ci*16 + n];
        h[n] = v.x; h[n+1] = v.y; h[n+2] = v.z; h[n+3] = v.w;
    }

    if (fast) {
        for (int t8 = 0; t8 < TCHUNK/8; ++t8) {
            size_t gi = ((size_t)b*(SEQ>>3) + c*(TCHUNK>>3) + t8)*(size_t)DINNER + d;
            us8 de8 = de8p[gi];
            us8 u8  = u8p[gi];
            #pragma unroll
            for (int j2 = 0; j2 < 8; j2++) {
                int l = c*TCHUNK + t8*8 + j2;
                const float* br = brow + (size_t)(t8*8 + j2)*96;   // wave-uniform
                float de = b2f(de8[j2]);
                float u  = b2f(u8[j2]);
                float du = de * u;
                float r  = exp2f(de * (-LOG2E));
                float e[16];
                pow_chain(r, e);
                float cc = 0.f;
                #pragma unroll
                for (int n = 0; n < 16; n++) {
                    h[n] = e[n]*h[n] + du*br[n];
                    cc  += h[n]*br[DSTATE + n];
                }
                float zv = silu_f(b2f(zN[baseN + (size_t)l*DINNER]));
                yN[baseN + (size_t)l*DINNER] = __float2bfloat16((cc + u*Dd) * zv);
            }
        }
    } else {
        for (int t8 = 0; t8 < TCHUNK/8; ++t8) {
            size_t gi = ((size_t)b*(SEQ>>3) + c*(TCHUNK>>3) + t8)*(size_t)DINNER + d;
            us8 de8 = de8p[gi];
            us8 u8  = u8p[gi];
            #pragma unroll
            for (int j2 = 0; j2 < 8; j2++) {
                int l = c*TCHUNK + t8*8 + j2;
                const float* br = brow + (size_t)(t8*8 + j2)*96;
                float de = b2f(de8[j2]);
                float u  = b2f(u8[j2]);
                float du = de * u;
                float cc = 0.f;
                #pragma unroll
                for (int n = 0; n < 16; n++) {
                    h[n] = exp2f(de*An[n])*h[n] + du*br[n];
                    cc  += h[n]*br[DSTATE + n];
                }
                float zv = silu_f(b2f(zN[baseN + (size_t)l*DINNER]));
                yN[baseN + (size_t)l*DINNER] = __float2bfloat16((cc + u*Dd) * zv);
            }
        }
    }
}

// ---------- diagnostic fallback ----------
__global__ __launch_bounds__(256)
void zero_out_kernel(float* out, int n) {
    int i = blockIdx.x * 256 + threadIdx.x;
    if (i < n) out[i] = 0.f;
}

extern "C" void kernel_launch(void* const* d_in, const int* in_sizes, int n_in,
                              void* d_out, int out_size, void* d_ws, size_t ws_size,
                              hipStream_t stream) {
    const float* x      = (const float*)d_in[0];
    const float* W_in   = (const float*)d_in[1];
    const float* conv_w = (const float*)d_in[2];
    const float* conv_b = (const float*)d_in[3];
    const float* W_x    = (const float*)d_in[4];
    const float* W_dt   = (const float*)d_in[5];
    const float* b_dt   = (const float*)d_in[6];
    const float* A_log  = (const float*)d_in[7];
    const float* D_par  = (const float*)d_in[8];
    const float* W_out  = (const float*)d_in[9];

    size_t szBig = (size_t)BLROWS * DINNER * 2;                   // 8.39 MB
    size_t szBc  = (size_t)B_SZ * NCHUNK * DINNER * DSTATE * 4;   // 8.39 MB
    size_t need  = 5*szBig                       // xbufN,zbufN,xsN,xsT,deT
                 + (size_t)BLROWS*96*4                        // dbc
                 + (size_t)NSLICE*BLROWS*96*4                 // dbc partials
                 + (size_t)BLROWS*DTRANK*2                    // dtH
                 + szBc + (size_t)B_SZ*NCHUNK*DINNER*4
                 + (size_t)BLROWS*DMODEL*2       // xH
                 + (size_t)2*DINNER*DMODEL*2     // WinH
                 + (size_t)128*DINNER*2          // WxH
                 + (size_t)DINNER*DTRANK*2       // WdtH
                 + (size_t)DMODEL*DINNER*2;      // WoutH   (~83 MB, ws is ~268 MB)

    if (ws_size < need) {
        zero_out_kernel<<<(out_size + 255)/256, 256, 0, stream>>>((float*)d_out, out_size);
        return;
    }

    char* w = (char*)d_ws;
    __hip_bfloat16* xbufN = (__hip_bfloat16*)w;  w += szBig;
    __hip_bfloat16* zbufN = (__hip_bfloat16*)w;  w += szBig;
    __hip_bfloat16* xsN   = (__hip_bfloat16*)w;  w += szBig;   // later y (in-place)
    __hip_bfloat16* xsT   = (__hip_bfloat16*)w;  w += szBig;
    __hip_bfloat16* deT   = (__hip_bfloat16*)w;  w += szBig;
    float*          dbc   = (float*)w;           w += (size_t)BLROWS * 96 * 4;
    float*          dbcP  = (float*)w;           w += (size_t)NSLICE * BLROWS * 96 * 4;
    __hip_bfloat16* dtH   = (__hip_bfloat16*)w;  w += (size_t)BLROWS * DTRANK * 2;
    float*          Bc    = (float*)w;           w += szBc;
    float*          sde   = (float*)w;           w += (size_t)B_SZ * NCHUNK * DINNER * 4;
    __hip_bfloat16* xH    = (__hip_bfloat16*)w;  w += (size_t)BLROWS*DMODEL*2;
    __hip_bfloat16* WinH  = (__hip_bfloat16*)w;  w += (size_t)2*DINNER*DMODEL*2;
    __hip_bfloat16* WxH   = (__hip_bfloat16*)w;  w += (size_t)128*DINNER*2;
    __hip_bfloat16* WdtH  = (__hip_bfloat16*)w;  w += (size_t)DINNER*DTRANK*2;
    __hip_bfloat16* WoutH = (__hip_bfloat16*)w;  w += (size_t)DMODEL*DINNER*2;
    __hip_bfloat16* yN    = xsN;

    // 0) fused init: all casts
    init_kernel<<<GTOT/256, 256, 0, stream>>>(x, W_in, W_x, W_dt, W_out,
        (unsigned short*)xH, (unsigned short*)WinH, (unsigned short*)WxH,
        (unsigned short*)WdtH, (unsigned short*)WoutH);

    // 1) xz = x @ W_in^T -> xbufN | zbufN. 128x128 tiles, 512 blocks, XCD-swizzled
    gemm_tn<128,128,5,false,true><<<dim3(BLROWS/128, (2*DINNER)/128, 1), 256, 0, stream>>>(
        xH, WinH, BLROWS, 2*DINNER, DMODEL, DMODEL, nullptr, xbufN, zbufN, nullptr);

    // 2) fused conv+silu+transpose: xbufN -> xsN + xsT (packed)
    conv_transpose_kernel<<<dim3(SEQ/64, DINNER/64, B_SZ), 256, 0, stream>>>(
        (const unsigned short*)xbufN, conv_w, conv_b,
        (unsigned short*)xsN, (unsigned short*)xsT);

    // 3) dbc partials = x_ssm @ W_x^T (N=96, split-K=16, plain stores; 512 blocks)
    //    then fused reduce + dt cvt
    gemm_tn<128,64,9,true><<<dim3(BLROWS/128, 2, NSLICE), 256, 0, stream>>>(
        xsN, WxH, BLROWS, 96, DINNER, DINNER/NSLICE, dbcP, nullptr, nullptr, nullptr);
    dbc_reduce_kernel<<<BLROWS/2, 192, 0, stream>>>(dbcP, dbc, dtH);

    // 4) delta = softplus(dt @ W_dt^T + b_dt) -> deT (packed) via LDS-transpose epilogue.
    gemm_tn<64,64,8,false><<<dim3(BLROWS/64, DINNER/64, 1), 256, 0, stream>>>(
        dtH, WdtH, BLROWS, DINNER, DTRANK, DTRANK, nullptr, deT, nullptr, b_dt);

    // 5) chunked selective scan, d-per-lane, packed coalesced loads. 512 blocks
    scan_pass1<<<B_SZ*NCHUNK*8, 256, 0, stream>>>((const unsigned short*)deT,
        (const unsigned short*)xsT, dbc, A_log, Bc, sde);
    scan_pass2<<<B_SZ*128, 256, 0, stream>>>(Bc, sde, A_log);
    scan_pass3<<<B_SZ*NCHUNK*8, 256, 0, stream>>>((const unsigned short*)deT,
        (const unsigned short*)xsT, dbc, A_log, D_par, Bc,
        (const unsigned short*)zbufN, yN);

    // 6) out = y @ W_out^T -> d_out. 64x64 tiles, 512 blocks, XCD-swizzled
    gemm_tn<64,64,9,false,true><<<dim3(BLROWS/64, DMODEL/64, 1), 256, 0, stream>>>(
        yN, WoutH, BLROWS, DMODEL, DINNER, DINNER, (float*)d_out, nullptr, nullptr, nullptr);
}